// Round 7
// baseline (133.790 us; speedup 1.0000x reference)
//
#include <hip/hip_runtime.h>
#include <hip/hip_bf16.h>

// Problem dims
#define BROWS 8192
#define IDIM 256
#define HDIM 512
#define KCAT 768    // I + H
#define G4 2048     // 4*H

typedef __bf16 bf16_t;
typedef bf16_t bf16x8 __attribute__((ext_vector_type(8)));
typedef float f32x4 __attribute__((ext_vector_type(4)));

__device__ __forceinline__ f32x4 mfma16(bf16x8 a, bf16x8 b, f32x4 c) {
    return __builtin_amdgcn_mfma_f32_16x16x32_bf16(a, b, c, 0, 0, 0);
}

__device__ __forceinline__ ushort f2bf(float f) {
    union { float f; unsigned u; } v; v.f = f;
    unsigned u = v.u;
    unsigned r = (u + 0x7fffu + ((u >> 16) & 1u)) >> 16;  // RNE, inputs finite
    return (ushort)r;
}

__device__ __forceinline__ float bf2f(ushort u) {
    union { unsigned u; float f; } v; v.u = (unsigned)u << 16; return v.f;
}

__device__ __forceinline__ float sigmoidf_(float x) {
    return 1.f / (1.f + __expf(-x));
}
__device__ __forceinline__ float tanhf_(float x) {
    return 1.f - 2.f / (__expf(2.f * x) + 1.f);   // safe at +/-inf
}

// async global -> LDS, 16 bytes per lane (lds dest: wave-uniform base + lane*16)
typedef __attribute__((address_space(1))) const unsigned gas_u32;
typedef __attribute__((address_space(3))) unsigned las_u32;
__device__ __forceinline__ void gld_lds16(const void* g, void* l) {
    __builtin_amdgcn_global_load_lds((gas_u32*)g, (las_u32*)l, 16, 0, 0);
}

// XCD-aware block decode: 64 rb x C cb grids, 1D-flattened
__device__ __forceinline__ void xcd_decode(int bid, int& rb, int& cb) {
    int xcd = bid & 7, local = bid >> 3;
    rb = xcd * 8 + (local & 7);
    cb = local >> 3;
}

// ---------------- shared K-loop: T3-minimal 2-phase (catalog recipe) ----------------
// Tile: 128 rows x (NFRAG*32) cols, BK=32, 4 waves (2x2), fragment-linear LDS
// (subtile = 16 rows x 32 k stored as 64 lanes x 16B -> 0 bank conflicts, R3-verified).
// Loop: stage(t+1) issued FIRST, then compute(t) (ds_read+MFMA) covers the
// t+1 load latency, then __syncthreads() (vmcnt(0)+lgkmcnt(0) drain + barrier)
// certifies tile t+1 landed and all waves done reading slot t before iter t+1
// overwrites slot (t+2)&1 == t&1. One drain+barrier per tile, drain AFTER compute.
template<int NFRAG>
__device__ __forceinline__ void gemm_kloop(
        const ushort* aH0, const ushort* aH1,
        const ushort* wH0, const ushort* wH1, int NT,
        ushort* As, ushort* Ws,
        int wm, int wn, int lane, int wave, f32x4 (*acc)[NFRAG]) {
    const int WSTR = NFRAG * 1024;   // ushorts per W buffer
    auto stage = [&](int buf, int t) {
        const int o = t * 32;
        gld_lds16(aH0 + o, As + buf * 4096 + wave * 512);
        gld_lds16(aH1 + o, As + buf * 4096 + 2048 + wave * 512);
        gld_lds16(wH0 + o, Ws + buf * WSTR + wave * 512);
        if (NFRAG == 4)
            gld_lds16(wH1 + o, Ws + buf * WSTR + 2048 + wave * 512);
    };
    auto compute = [&](int buf) {
        bf16x8 af[4], wf[NFRAG];
#pragma unroll
        for (int t = 0; t < 4; t++)
            af[t] = *(const bf16x8*)&As[buf * 4096 + (wm * 4 + t) * 512 + lane * 8];
#pragma unroll
        for (int t = 0; t < NFRAG; t++)
            wf[t] = *(const bf16x8*)&Ws[buf * WSTR + (wn * NFRAG + t) * 512 + lane * 8];
#pragma unroll
        for (int m = 0; m < 4; m++)
#pragma unroll
            for (int n = 0; n < NFRAG; n++)
                acc[m][n] = mfma16(af[m], wf[n], acc[m][n]);
    };
    stage(0, 0);
    __syncthreads();                    // tile 0 landed
    for (int t = 0; t < NT; t++) {
        if (t + 1 < NT) stage((t + 1) & 1, t + 1);   // issue next-tile loads
        compute(t & 1);                               // hide latency under MFMA
        __syncthreads();                              // t+1 ready; slot t free
    }
}

// ---------------- prep: fp32 -> bf16 packing (float4 vectorized) ----------------
__global__ void __launch_bounds__(256) prep_kernel(
        const float* __restrict__ x, const float* __restrict__ h,
        const float* __restrict__ aw0, const float* __restrict__ aw1,
        const float* __restrict__ w_ih, const float* __restrict__ w_hh,
        const float* __restrict__ ow0,
        ushort* __restrict__ xh, ushort* __restrict__ baw0,
        ushort* __restrict__ baw1, ushort* __restrict__ wcat,
        ushort* __restrict__ bow0) {
    int idx = (blockIdx.x * 256 + threadIdx.x) * 4;
    const int N_XH = BROWS * KCAT;      // 6291456
    const int N_AW0 = IDIM * KCAT;      // 196608
    const int N_AW1 = IDIM * IDIM;      // 65536
    const int N_WCAT = G4 * KCAT;       // 1572864
    const int N_OW0 = HDIM * HDIM;      // 262144
    float4 v;
    ushort* dst;
    if (idx < N_XH) {
        int b = idx / KCAT, k = idx - b * KCAT;
        v = (k < IDIM) ? *(const float4*)&x[b * IDIM + k]
                       : *(const float4*)&h[b * HDIM + (k - IDIM)];
        dst = &xh[idx];
    } else if ((idx -= N_XH) < N_AW0) {
        v = *(const float4*)&aw0[idx]; dst = &baw0[idx];
    } else if ((idx -= N_AW0) < N_AW1) {
        v = *(const float4*)&aw1[idx]; dst = &baw1[idx];
    } else if ((idx -= N_AW1) < N_WCAT) {
        int o = idx / KCAT, k = idx - o * KCAT;
        v = (k < IDIM) ? *(const float4*)&w_ih[o * IDIM + k]
                       : *(const float4*)&w_hh[o * HDIM + (k - IDIM)];
        dst = &wcat[idx];
    } else if ((idx -= N_WCAT) < N_OW0) {
        v = *(const float4*)&ow0[idx]; dst = &bow0[idx];
    } else {
        return;
    }
    ushort4 o4 = { f2bf(v.x), f2bf(v.y), f2bf(v.z), f2bf(v.w) };
    *(ushort4*)dst = o4;
}

// ---------------- staged GEMM: C = act(A @ W^T + bias) ----------------
template<int RELU_BF16, int NFRAG>
__global__ void __launch_bounds__(256) staged_gemm(
        const ushort* __restrict__ A, const ushort* __restrict__ W,
        const float* __restrict__ bias, void* __restrict__ outp,
        int Kdim, int out_ld) {
    __shared__ ushort As[2 * 4096];
    __shared__ ushort Ws[2 * NFRAG * 1024];
    const int tid = threadIdx.x;
    const int lane = tid & 63, wave = tid >> 6;
    const int wm = wave >> 1, wn = wave & 1;
    const int r = lane & 15, g = lane >> 4;
    int rb, cb;
    xcd_decode(blockIdx.x, rb, cb);
    const int row0 = rb * 128, col0 = cb * (NFRAG * 32);

    const ushort* aH0 = A + (size_t)(row0 + wave * 16 + r) * Kdim + g * 8;
    const ushort* aH1 = aH0 + (size_t)64 * Kdim;
    const ushort* wH0 = W + (size_t)(col0 + wave * 16 + r) * Kdim + g * 8;
    const ushort* wH1 = wH0 + (size_t)64 * Kdim;   // unused when NFRAG==2

    f32x4 acc[4][NFRAG] = {};
    gemm_kloop<NFRAG>(aH0, aH1, wH0, wH1, Kdim >> 5, As, Ws, wm, wn, lane, wave, acc);

#pragma unroll
    for (int n = 0; n < NFRAG; n++) {
        int col = col0 + wn * (NFRAG * 16) + n * 16 + r;
        float bv = bias[col];
#pragma unroll
        for (int m = 0; m < 4; m++) {
            int rbase = row0 + wm * 64 + m * 16 + g * 4;
#pragma unroll
            for (int reg = 0; reg < 4; reg++) {
                float v = acc[m][n][reg] + bv;
                if (RELU_BF16) {
                    v = v > 0.f ? v : 0.f;
                    ((ushort*)outp)[(size_t)(rbase + reg) * out_ld + col] = f2bf(v);
                } else {
                    ((float*)outp)[(size_t)(rbase + reg) * out_ld + col] = v;
                }
            }
        }
    }
}

// ---------------- rowwise softmax + attn out + x_att into xh ----------------
__global__ void __launch_bounds__(256) attn_softmax(
        const float* __restrict__ logits, const float* __restrict__ x,
        float* __restrict__ attn_out, ushort* __restrict__ xh) {
    const int wave = threadIdx.x >> 6, lane = threadIdx.x & 63;
    const int row = blockIdx.x * 4 + wave;
    float v[4];
    float m = -1e30f;
#pragma unroll
    for (int i = 0; i < 4; i++) {
        v[i] = logits[row * IDIM + i * 64 + lane];
        m = fmaxf(m, v[i]);
    }
#pragma unroll
    for (int s = 32; s; s >>= 1) m = fmaxf(m, __shfl_xor(m, s, 64));
    float sum = 0.f;
#pragma unroll
    for (int i = 0; i < 4; i++) { v[i] = __expf(v[i] - m); sum += v[i]; }
#pragma unroll
    for (int s = 32; s; s >>= 1) sum += __shfl_xor(sum, s, 64);
    float inv = 1.f / sum;
#pragma unroll
    for (int i = 0; i < 4; i++) {
        int idx = i * 64 + lane;
        float a = v[i] * inv;
        attn_out[row * IDIM + idx] = a;
        xh[row * KCAT + idx] = f2bf(x[row * IDIM + idx] * a);
    }
}

// ---------------- fused gates GEMM + LSTM epilogue ----------------
// gates = [x_att|h] @ [w_ih|w_hh]^T : M=8192, j=512, 4 gates, K=768.
// 128 rows x 128 cols (4 gates x 32 j), 4 waves, 2-slot 32KB LDS,
// grid 64x16 = 1024 blocks = 4/CU co-resident (no tail).
// Column remap puts gate index on fragment index n: acc[m][0..3] = (i,f,g,o).
__global__ void __launch_bounds__(256) gates_staged(
        const ushort* __restrict__ A, const ushort* __restrict__ W,
        const float* __restrict__ b_ih, const float* __restrict__ b_hh,
        const float* __restrict__ c_in,
        float* __restrict__ h_out, float* __restrict__ c_out,
        ushort* __restrict__ h_bf) {
    __shared__ ushort As[2 * 4096];
    __shared__ ushort Ws[2 * 4096];
    const int tid = threadIdx.x;
    const int lane = tid & 63, wave = tid >> 6;
    const int wm = wave >> 1, wn = wave & 1;
    const int r = lane & 15, g = lane >> 4;
    int rb, cb;
    xcd_decode(blockIdx.x, rb, cb);
    const int row0 = rb * 128;
    const int j0 = cb * 32;

    auto wrow = [&](int cc) {
        return ((cc >> 4) & 3) * HDIM + j0 + (cc & 15) + ((cc >> 6) << 4);
    };
    const ushort* aH0 = A + (size_t)(row0 + wave * 16 + r) * KCAT + g * 8;
    const ushort* aH1 = aH0 + (size_t)64 * KCAT;
    const ushort* wH0 = W + (size_t)wrow(wave * 16 + r) * KCAT + g * 8;
    const ushort* wH1 = W + (size_t)wrow(64 + wave * 16 + r) * KCAT + g * 8;

    f32x4 acc[4][4] = {};
    gemm_kloop<4>(aH0, aH1, wH0, wH1, KCAT >> 5, As, Ws, wm, wn, lane, wave, acc);

    // LSTM epilogue: lane-local. j fixed per lane; gate = fragment index n.
    const int j = j0 + wn * 16 + r;
    float bb[4];
#pragma unroll
    for (int n = 0; n < 4; n++) bb[n] = b_ih[n * HDIM + j] + b_hh[n * HDIM + j];
#pragma unroll
    for (int m = 0; m < 4; m++) {
        int rbase = row0 + wm * 64 + m * 16 + g * 4;
#pragma unroll
        for (int reg = 0; reg < 4; reg++) {
            int row = rbase + reg;
            float ig = sigmoidf_(acc[m][0][reg] + bb[0]);
            float fg = sigmoidf_(acc[m][1][reg] + bb[1]);
            float gg = tanhf_(acc[m][2][reg] + bb[2]);
            float og = sigmoidf_(acc[m][3][reg] + bb[3]);
            float cn = fg * c_in[(size_t)row * HDIM + j] + ig * gg;
            float hn = og * tanhf_(cn);
            c_out[(size_t)row * HDIM + j] = cn;
            h_out[(size_t)row * HDIM + j] = hn;
            h_bf[(size_t)row * HDIM + j] = f2bf(hn);
        }
    }
}

// ---------------- head GEMV: out = sigmoid(hrelu . ow1 + ob1) ----------------
__global__ void __launch_bounds__(256) head_gemv(
        const ushort* __restrict__ Hrelu, const float* __restrict__ ow1,
        const float* __restrict__ ob1, float* __restrict__ outp) {
    const int wave = threadIdx.x >> 6, lane = threadIdx.x & 63;
    const int row = blockIdx.x * 4 + wave;
    typedef ushort u16x8 __attribute__((ext_vector_type(8)));
    u16x8 hv = *(const u16x8*)&Hrelu[(size_t)row * HDIM + lane * 8];
    float4 w0 = *(const float4*)&ow1[lane * 8];
    float4 w1 = *(const float4*)&ow1[lane * 8 + 4];
    float s = bf2f(hv[0]) * w0.x + bf2f(hv[1]) * w0.y + bf2f(hv[2]) * w0.z +
              bf2f(hv[3]) * w0.w + bf2f(hv[4]) * w1.x + bf2f(hv[5]) * w1.y +
              bf2f(hv[6]) * w1.z + bf2f(hv[7]) * w1.w;
#pragma unroll
    for (int sh = 32; sh; sh >>= 1) s += __shfl_xor(s, sh, 64);
    if (lane == 0) outp[row] = 1.f / (1.f + __expf(-(s + ob1[0])));
}

extern "C" void kernel_launch(void* const* d_in, const int* in_sizes, int n_in,
                              void* d_out, int out_size, void* d_ws, size_t ws_size,
                              hipStream_t stream) {
    const float* x    = (const float*)d_in[0];
    const float* h    = (const float*)d_in[1];
    const float* c    = (const float*)d_in[2];
    const float* aw0  = (const float*)d_in[3];
    const float* ab0  = (const float*)d_in[4];
    const float* aw1  = (const float*)d_in[5];
    const float* ab1  = (const float*)d_in[6];
    const float* w_ih = (const float*)d_in[7];
    const float* b_ih = (const float*)d_in[8];
    const float* w_hh = (const float*)d_in[9];
    const float* b_hh = (const float*)d_in[10];
    const float* ow0  = (const float*)d_in[11];
    const float* ob0  = (const float*)d_in[12];
    const float* ow1  = (const float*)d_in[13];
    const float* ob1  = (const float*)d_in[14];

    char* ws = (char*)d_ws;
    ushort* xh     = (ushort*)(ws + 0);           // 8192*768*2  = 12582912
    ushort* a0     = (ushort*)(ws + 12582912);    // 8192*256*2  = 4194304
    float*  logits = (float*) (ws + 16777216);    // 8192*256*4  = 8388608
    ushort* hrelu  = (ushort*)(ws + 16777216);    // aliases logits (dead after softmax)
    ushort* hbf    = (ushort*)(ws + 25165824);    // 8192*512*2  = 8388608
    ushort* baw0   = (ushort*)(ws + 33554432);    // 256*768*2   = 393216
    ushort* baw1   = (ushort*)(ws + 33947648);    // 256*256*2   = 131072
    ushort* wcat   = (ushort*)(ws + 34078720);    // 2048*768*2  = 3145728
    ushort* bow0   = (ushort*)(ws + 37224448);    // 512*512*2   = 524288

    float* outv    = (float*)d_out;               // [8192]
    float* h_out   = outv + 8192;                 // [8192,512]
    float* c_out   = outv + 4202496;              // [8192,512]
    float* attn_o  = outv + 8396800;              // [8192,256]

    prep_kernel<<<8192, 256, 0, stream>>>(x, h, aw0, aw1, w_ih, w_hh, ow0,
                                          xh, baw0, baw1, wcat, bow0);
    // a0 = relu(xh @ aw0^T + ab0)         M=8192 N=256 K=768 -> 64x4 = 256 blocks
    staged_gemm<1, 2><<<256, 256, 0, stream>>>(xh, baw0, ab0, a0, KCAT, IDIM);
    // logits = a0 @ aw1^T + ab1           M=8192 N=256 K=256 -> 64x4 = 256 blocks
    staged_gemm<0, 2><<<256, 256, 0, stream>>>(a0, baw1, ab1, logits, IDIM, IDIM);
    attn_softmax<<<2048, 256, 0, stream>>>(logits, x, attn_o, xh);
    // fused LSTM gates                    M=8192 N=2048 K=768 -> 64x16 = 1024 blocks
    gates_staged<<<1024, 256, 0, stream>>>(xh, wcat, b_ih, b_hh, c,
                                           h_out, c_out, hbf);
    // hrelu = relu(h_new @ ow0^T + ob0)   M=8192 N=512 K=512 -> 64x4 = 256 blocks
    staged_gemm<1, 4><<<256, 256, 0, stream>>>(hbf, bow0, ob0, hrelu, HDIM, HDIM);
    head_gemv<<<2048, 256, 0, stream>>>(hrelu, ow1, ob1, outv);
}

// Round 8
// 110.350 us; speedup vs baseline: 1.2124x; 1.2124x over previous
//
#include <hip/hip_runtime.h>
#include <hip/hip_bf16.h>

// Problem dims
#define BROWS 8192
#define IDIM 256
#define HDIM 512
#define KCAT 768    // I + H
#define G4 2048     // 4*H

typedef __bf16 bf16_t;
typedef bf16_t bf16x8 __attribute__((ext_vector_type(8)));
typedef float f32x4 __attribute__((ext_vector_type(4)));

__device__ __forceinline__ f32x4 mfma16(bf16x8 a, bf16x8 b, f32x4 c) {
    return __builtin_amdgcn_mfma_f32_16x16x32_bf16(a, b, c, 0, 0, 0);
}

__device__ __forceinline__ ushort f2bf(float f) {
    union { float f; unsigned u; } v; v.f = f;
    unsigned u = v.u;
    unsigned r = (u + 0x7fffu + ((u >> 16) & 1u)) >> 16;  // RNE, inputs finite
    return (ushort)r;
}

__device__ __forceinline__ float bf2f(ushort u) {
    union { unsigned u; float f; } v; v.u = (unsigned)u << 16; return v.f;
}

__device__ __forceinline__ float sigmoidf_(float x) {
    return 1.f / (1.f + __expf(-x));
}
__device__ __forceinline__ float tanhf_(float x) {
    return 1.f - 2.f / (__expf(2.f * x) + 1.f);   // safe at +/-inf
}

// async global -> LDS, 16 bytes per lane (lds dest: wave-uniform base + lane*16)
typedef __attribute__((address_space(1))) const unsigned gas_u32;
typedef __attribute__((address_space(3))) unsigned las_u32;
__device__ __forceinline__ void gld_lds16(const void* g, void* l) {
    __builtin_amdgcn_global_load_lds((gas_u32*)g, (las_u32*)l, 16, 0, 0);
}

// ---------------- Swizzle scheme (both-sides, rule #21) ----------------
// Staging (global->LDS): lane L of a wave writes LDS byte base + L*16 (linear,
// conflict-free). lane L covers row rW = L>>2, chunk-slot s = L&3 of a 16-row
// x 64B subtile. The GLOBAL source chunk is pre-swizzled: c = s ^ ((rW>>1)&3)
// -- same 64B line as unswizzled (adjacent-lane coalescing preserved).
// Fragment read: lane (r = lane&15, g = lane>>4) reads 16B at
// r*64 + (g ^ ((r>>1)&3))*16 bytes -> bank-quads spread 8-wide, 2 lanes/quad
// per quarter-wave = conflict-free (m136: 2-way is free).

// ---------------- prep: fp32 -> bf16 packing (float4 vectorized) ----------------
__global__ void __launch_bounds__(256) prep_kernel(
        const float* __restrict__ x, const float* __restrict__ h,
        const float* __restrict__ aw0, const float* __restrict__ aw1,
        const float* __restrict__ w_ih, const float* __restrict__ w_hh,
        const float* __restrict__ ow0,
        ushort* __restrict__ xh, ushort* __restrict__ baw0,
        ushort* __restrict__ baw1, ushort* __restrict__ wcat,
        ushort* __restrict__ bow0) {
    int idx = (blockIdx.x * 256 + threadIdx.x) * 4;
    const int N_XH = BROWS * KCAT;      // 6291456
    const int N_AW0 = IDIM * KCAT;      // 196608
    const int N_AW1 = IDIM * IDIM;      // 65536
    const int N_WCAT = G4 * KCAT;       // 1572864
    const int N_OW0 = HDIM * HDIM;      // 262144
    float4 v;
    ushort* dst;
    if (idx < N_XH) {
        int b = idx / KCAT, k = idx - b * KCAT;
        v = (k < IDIM) ? *(const float4*)&x[b * IDIM + k]
                       : *(const float4*)&h[b * HDIM + (k - IDIM)];
        dst = &xh[idx];
    } else if ((idx -= N_XH) < N_AW0) {
        v = *(const float4*)&aw0[idx]; dst = &baw0[idx];
    } else if ((idx -= N_AW0) < N_AW1) {
        v = *(const float4*)&aw1[idx]; dst = &baw1[idx];
    } else if ((idx -= N_AW1) < N_WCAT) {
        int o = idx / KCAT, k = idx - o * KCAT;
        v = (k < IDIM) ? *(const float4*)&w_ih[o * IDIM + k]
                       : *(const float4*)&w_hh[o * HDIM + (k - IDIM)];
        dst = &wcat[idx];
    } else if ((idx -= N_WCAT) < N_OW0) {
        v = *(const float4*)&ow0[idx]; dst = &bow0[idx];
    } else {
        return;
    }
    ushort4 o4 = { f2bf(v.x), f2bf(v.y), f2bf(v.z), f2bf(v.w) };
    *(ushort4*)dst = o4;
}

// ---------------- staged GEMM: C = act(A @ W^T + bias) ----------------
// R2-exact structure: 128 x (NFRAG*32) tile, 4 waves 2x2, 2-buf LDS,
// block-cooperative coalesced staging, stage->compute->__syncthreads loop.
// + chunk-XOR swizzle (see header) for conflict-free fragment reads.
template<int RELU_BF16, int NFRAG>
__global__ void __launch_bounds__(256) staged_gemm(
        const ushort* __restrict__ A, const ushort* __restrict__ W,
        const float* __restrict__ bias, void* __restrict__ outp,
        int Kdim, int out_ld) {
    __shared__ ushort As[2][4096];
    __shared__ ushort Ws[2][NFRAG * 1024];
    const int tid = threadIdx.x;
    const int lane = tid & 63, wave = tid >> 6;
    const int wm = wave >> 1, wn = wave & 1;
    const int r = lane & 15, g = lane >> 4;
    const int rb = blockIdx.x & 63, cb = blockIdx.x >> 6;
    const int row0 = rb * 128, col0 = cb * (NFRAG * 32);
    const int s_row = tid >> 2;                           // 0..63
    const int s_sw = ((tid & 3) ^ ((s_row >> 1) & 3)) * 8; // swizzled chunk (ushorts)

    const ushort* aBase = A + (size_t)(row0 + s_row) * Kdim + s_sw;
    const ushort* wBase = W + (size_t)(col0 + s_row) * Kdim + s_sw;
    const int step64 = 64 * Kdim;
    const int rsw = (g ^ ((r >> 1) & 3)) * 8;             // read-side swizzle

    f32x4 acc[4][NFRAG] = {};

    auto stage = [&](int buf, int t) {
        const int o = t * 32;
        gld_lds16(aBase + o,          &As[buf][wave * 512]);
        gld_lds16(aBase + o + step64, &As[buf][2048 + wave * 512]);
        gld_lds16(wBase + o,          &Ws[buf][wave * 512]);
        if (NFRAG == 4)
            gld_lds16(wBase + o + step64, &Ws[buf][2048 + wave * 512]);
    };
    auto compute = [&](int buf) {
        bf16x8 af[4], wf[NFRAG];
#pragma unroll
        for (int t = 0; t < 4; t++)
            af[t] = *(const bf16x8*)&As[buf][(wm * 4 + t) * 512 + r * 32 + rsw];
#pragma unroll
        for (int t = 0; t < NFRAG; t++)
            wf[t] = *(const bf16x8*)&Ws[buf][(wn * NFRAG + t) * 512 + r * 32 + rsw];
#pragma unroll
        for (int m = 0; m < 4; m++)
#pragma unroll
            for (int n = 0; n < NFRAG; n++)
                acc[m][n] = mfma16(af[m], wf[n], acc[m][n]);
    };

    stage(0, 0);
    __syncthreads();
    const int NT = Kdim >> 5;
    int cur = 0;
    for (int t = 0; t < NT - 1; t++) {
        stage(cur ^ 1, t + 1);
        compute(cur);
        __syncthreads();
        cur ^= 1;
    }
    compute(cur);

#pragma unroll
    for (int n = 0; n < NFRAG; n++) {
        int col = col0 + wn * (NFRAG * 16) + n * 16 + r;
        float bv = bias[col];
#pragma unroll
        for (int m = 0; m < 4; m++) {
            int rbase = row0 + wm * 64 + m * 16 + g * 4;
#pragma unroll
            for (int reg = 0; reg < 4; reg++) {
                float v = acc[m][n][reg] + bv;
                if (RELU_BF16) {
                    v = v > 0.f ? v : 0.f;
                    ((ushort*)outp)[(size_t)(rbase + reg) * out_ld + col] = f2bf(v);
                } else {
                    ((float*)outp)[(size_t)(rbase + reg) * out_ld + col] = v;
                }
            }
        }
    }
}

// ---------------- rowwise softmax + attn out + x_att into xh ----------------
__global__ void __launch_bounds__(256) attn_softmax(
        const float* __restrict__ logits, const float* __restrict__ x,
        float* __restrict__ attn_out, ushort* __restrict__ xh) {
    const int wave = threadIdx.x >> 6, lane = threadIdx.x & 63;
    const int row = blockIdx.x * 4 + wave;
    float v[4];
    float m = -1e30f;
#pragma unroll
    for (int i = 0; i < 4; i++) {
        v[i] = logits[row * IDIM + i * 64 + lane];
        m = fmaxf(m, v[i]);
    }
#pragma unroll
    for (int s = 32; s; s >>= 1) m = fmaxf(m, __shfl_xor(m, s, 64));
    float sum = 0.f;
#pragma unroll
    for (int i = 0; i < 4; i++) { v[i] = __expf(v[i] - m); sum += v[i]; }
#pragma unroll
    for (int s = 32; s; s >>= 1) sum += __shfl_xor(sum, s, 64);
    float inv = 1.f / sum;
#pragma unroll
    for (int i = 0; i < 4; i++) {
        int idx = i * 64 + lane;
        float a = v[i] * inv;
        attn_out[row * IDIM + idx] = a;
        xh[row * KCAT + idx] = f2bf(x[row * IDIM + idx] * a);
    }
}

// ---------------- fused gates GEMM + LSTM epilogue ----------------
// gates = [x_att|h] @ [w_ih|w_hh]^T : M=8192, j=512, 4 gates, K=768.
// R2-exact: 128x128 tile (4 gates x 32 j), 4 waves, 2-buf 32KB LDS,
// grid dim3(64,16) = 1024 blocks = 4/CU, stage->compute->sync loop.
// + chunk-XOR swizzle. Column remap puts gate on fragment index n:
// acc[m][0..3] = (i,f,g,o) -> lane-local LSTM epilogue.
__global__ void __launch_bounds__(256) gates_staged(
        const ushort* __restrict__ A, const ushort* __restrict__ W,
        const float* __restrict__ b_ih, const float* __restrict__ b_hh,
        const float* __restrict__ c_in,
        float* __restrict__ h_out, float* __restrict__ c_out,
        ushort* __restrict__ h_bf) {
    __shared__ ushort As[2][4096];
    __shared__ ushort Ws[2][4096];
    const int tid = threadIdx.x;
    const int lane = tid & 63, wave = tid >> 6;
    const int wm = wave >> 1, wn = wave & 1;
    const int r = lane & 15, g = lane >> 4;
    const int row0 = blockIdx.x * 128;
    const int j0 = blockIdx.y * 32;
    const int s_row = tid >> 2;                            // 0..63
    const int s_sw = ((tid & 3) ^ ((s_row >> 1) & 3)) * 8; // swizzled chunk
    const int rsw = (g ^ ((r >> 1) & 3)) * 8;              // read-side swizzle

    auto wrow = [&](int cc) {
        return ((cc >> 4) & 3) * HDIM + j0 + (cc & 15) + ((cc >> 6) << 4);
    };
    const ushort* aBase = A + (size_t)(row0 + s_row) * KCAT + s_sw;
    const ushort* w0p = W + (size_t)wrow(s_row) * KCAT + s_sw;
    const ushort* w1p = W + (size_t)wrow(s_row + 64) * KCAT + s_sw;

    f32x4 acc[4][4] = {};

    auto stage = [&](int buf, int t) {
        const int o = t * 32;
        gld_lds16(aBase + o,             &As[buf][wave * 512]);
        gld_lds16(aBase + o + 64 * KCAT, &As[buf][2048 + wave * 512]);
        gld_lds16(w0p + o,               &Ws[buf][wave * 512]);
        gld_lds16(w1p + o,               &Ws[buf][2048 + wave * 512]);
    };
    auto compute = [&](int buf) {
        bf16x8 af[4], wf[4];
#pragma unroll
        for (int t = 0; t < 4; t++)
            af[t] = *(const bf16x8*)&As[buf][(wm * 4 + t) * 512 + r * 32 + rsw];
#pragma unroll
        for (int t = 0; t < 4; t++)
            wf[t] = *(const bf16x8*)&Ws[buf][(wn * 4 + t) * 512 + r * 32 + rsw];
#pragma unroll
        for (int m = 0; m < 4; m++)
#pragma unroll
            for (int n = 0; n < 4; n++)
                acc[m][n] = mfma16(af[m], wf[n], acc[m][n]);
    };

    stage(0, 0);
    __syncthreads();
    const int NT = KCAT >> 5;   // 24
    int cur = 0;
    for (int t = 0; t < NT - 1; t++) {
        stage(cur ^ 1, t + 1);
        compute(cur);
        __syncthreads();
        cur ^= 1;
    }
    compute(cur);

    // LSTM epilogue: lane-local. j fixed per lane; gate = fragment index n.
    const int j = j0 + wn * 16 + r;
    float bb[4];
#pragma unroll
    for (int n = 0; n < 4; n++) bb[n] = b_ih[n * HDIM + j] + b_hh[n * HDIM + j];
#pragma unroll
    for (int m = 0; m < 4; m++) {
        int rbase = row0 + wm * 64 + m * 16 + g * 4;
#pragma unroll
        for (int reg = 0; reg < 4; reg++) {
            int row = rbase + reg;
            float ig = sigmoidf_(acc[m][0][reg] + bb[0]);
            float fg = sigmoidf_(acc[m][1][reg] + bb[1]);
            float gg = tanhf_(acc[m][2][reg] + bb[2]);
            float og = sigmoidf_(acc[m][3][reg] + bb[3]);
            float cn = fg * c_in[(size_t)row * HDIM + j] + ig * gg;
            float hn = og * tanhf_(cn);
            c_out[(size_t)row * HDIM + j] = cn;
            h_out[(size_t)row * HDIM + j] = hn;
            h_bf[(size_t)row * HDIM + j] = f2bf(hn);
        }
    }
}

// ---------------- head GEMV: out = sigmoid(hrelu . ow1 + ob1) ----------------
__global__ void __launch_bounds__(256) head_gemv(
        const ushort* __restrict__ Hrelu, const float* __restrict__ ow1,
        const float* __restrict__ ob1, float* __restrict__ outp) {
    const int wave = threadIdx.x >> 6, lane = threadIdx.x & 63;
    const int row = blockIdx.x * 4 + wave;
    typedef ushort u16x8 __attribute__((ext_vector_type(8)));
    u16x8 hv = *(const u16x8*)&Hrelu[(size_t)row * HDIM + lane * 8];
    float4 w0 = *(const float4*)&ow1[lane * 8];
    float4 w1 = *(const float4*)&ow1[lane * 8 + 4];
    float s = bf2f(hv[0]) * w0.x + bf2f(hv[1]) * w0.y + bf2f(hv[2]) * w0.z +
              bf2f(hv[3]) * w0.w + bf2f(hv[4]) * w1.x + bf2f(hv[5]) * w1.y +
              bf2f(hv[6]) * w1.z + bf2f(hv[7]) * w1.w;
#pragma unroll
    for (int sh = 32; sh; sh >>= 1) s += __shfl_xor(s, sh, 64);
    if (lane == 0) outp[row] = 1.f / (1.f + __expf(-(s + ob1[0])));
}

extern "C" void kernel_launch(void* const* d_in, const int* in_sizes, int n_in,
                              void* d_out, int out_size, void* d_ws, size_t ws_size,
                              hipStream_t stream) {
    const float* x    = (const float*)d_in[0];
    const float* h    = (const float*)d_in[1];
    const float* c    = (const float*)d_in[2];
    const float* aw0  = (const float*)d_in[3];
    const float* ab0  = (const float*)d_in[4];
    const float* aw1  = (const float*)d_in[5];
    const float* ab1  = (const float*)d_in[6];
    const float* w_ih = (const float*)d_in[7];
    const float* b_ih = (const float*)d_in[8];
    const float* w_hh = (const float*)d_in[9];
    const float* b_hh = (const float*)d_in[10];
    const float* ow0  = (const float*)d_in[11];
    const float* ob0  = (const float*)d_in[12];
    const float* ow1  = (const float*)d_in[13];
    const float* ob1  = (const float*)d_in[14];

    char* ws = (char*)d_ws;
    ushort* xh     = (ushort*)(ws + 0);           // 8192*768*2  = 12582912
    ushort* a0     = (ushort*)(ws + 12582912);    // 8192*256*2  = 4194304
    float*  logits = (float*) (ws + 16777216);    // 8192*256*4  = 8388608
    ushort* hrelu  = (ushort*)(ws + 16777216);    // aliases logits (dead after softmax)
    ushort* hbf    = (ushort*)(ws + 25165824);    // 8192*512*2  = 8388608
    ushort* baw0   = (ushort*)(ws + 33554432);    // 256*768*2   = 393216
    ushort* baw1   = (ushort*)(ws + 33947648);    // 256*256*2   = 131072
    ushort* wcat   = (ushort*)(ws + 34078720);    // 2048*768*2  = 3145728
    ushort* bow0   = (ushort*)(ws + 37224448);    // 512*512*2   = 524288

    float* outv    = (float*)d_out;               // [8192]
    float* h_out   = outv + 8192;                 // [8192,512]
    float* c_out   = outv + 4202496;              // [8192,512]
    float* attn_o  = outv + 8396800;              // [8192,256]

    prep_kernel<<<8192, 256, 0, stream>>>(x, h, aw0, aw1, w_ih, w_hh, ow0,
                                          xh, baw0, baw1, wcat, bow0);
    // a0 = relu(xh @ aw0^T + ab0)         M=8192 N=256 K=768 -> 64x4 = 256 blocks
    staged_gemm<1, 2><<<256, 256, 0, stream>>>(xh, baw0, ab0, a0, KCAT, IDIM);
    // logits = a0 @ aw1^T + ab1           M=8192 N=256 K=256 -> 64x4 = 256 blocks
    staged_gemm<0, 2><<<256, 256, 0, stream>>>(a0, baw1, ab1, logits, IDIM, IDIM);
    attn_softmax<<<2048, 256, 0, stream>>>(logits, x, attn_o, xh);
    // fused LSTM gates                    M=8192 N=2048 K=768 -> 64x16 = 1024 blocks
    gates_staged<<<dim3(64, 16), 256, 0, stream>>>(xh, wcat, b_ih, b_hh, c,
                                                   h_out, c_out, hbf);
    // hrelu = relu(h_new @ ow0^T + ob0)   M=8192 N=512 K=512 -> 64x4 = 256 blocks
    staged_gemm<1, 4><<<256, 256, 0, stream>>>(hbf, bow0, ob0, hrelu, HDIM, HDIM);
    head_gemv<<<2048, 256, 0, stream>>>(hrelu, ow1, ob1, outv);
}

// Round 9
// 103.237 us; speedup vs baseline: 1.2959x; 1.0689x over previous
//
#include <hip/hip_runtime.h>
#include <hip/hip_bf16.h>

// Problem dims
#define BROWS 8192
#define IDIM 256
#define HDIM 512
#define KCAT 768    // I + H
#define G4 2048     // 4*H

typedef __bf16 bf16_t;
typedef bf16_t bf16x8 __attribute__((ext_vector_type(8)));
typedef float f32x4 __attribute__((ext_vector_type(4)));

__device__ __forceinline__ f32x4 mfma16(bf16x8 a, bf16x8 b, f32x4 c) {
    return __builtin_amdgcn_mfma_f32_16x16x32_bf16(a, b, c, 0, 0, 0);
}

__device__ __forceinline__ ushort f2bf(float f) {
    union { float f; unsigned u; } v; v.f = f;
    unsigned u = v.u;
    unsigned r = (u + 0x7fffu + ((u >> 16) & 1u)) >> 16;  // RNE, inputs finite
    return (ushort)r;
}

__device__ __forceinline__ float bf2f(ushort u) {
    union { unsigned u; float f; } v; v.u = (unsigned)u << 16; return v.f;
}

__device__ __forceinline__ float sigmoidf_(float x) {
    return 1.f / (1.f + __expf(-x));
}
__device__ __forceinline__ float tanhf_(float x) {
    return 1.f - 2.f / (__expf(2.f * x) + 1.f);   // safe at +/-inf
}

// async global -> LDS, 16 bytes per lane (lds dest: wave-uniform base + lane*16)
typedef __attribute__((address_space(1))) const unsigned gas_u32;
typedef __attribute__((address_space(3))) unsigned las_u32;
__device__ __forceinline__ void gld_lds16(const void* g, void* l) {
    __builtin_amdgcn_global_load_lds((gas_u32*)g, (las_u32*)l, 16, 0, 0);
}

// ---------------- prep: fp32 -> bf16 packing (float4 vectorized) ----------------
__global__ void __launch_bounds__(256) prep_kernel(
        const float* __restrict__ x, const float* __restrict__ h,
        const float* __restrict__ aw0, const float* __restrict__ aw1,
        const float* __restrict__ w_ih, const float* __restrict__ w_hh,
        const float* __restrict__ ow0,
        ushort* __restrict__ xh, ushort* __restrict__ baw0,
        ushort* __restrict__ baw1, ushort* __restrict__ wcat,
        ushort* __restrict__ bow0) {
    int idx = (blockIdx.x * 256 + threadIdx.x) * 4;
    const int N_XH = BROWS * KCAT;      // 6291456
    const int N_AW0 = IDIM * KCAT;      // 196608
    const int N_AW1 = IDIM * IDIM;      // 65536
    const int N_WCAT = G4 * KCAT;       // 1572864
    const int N_OW0 = HDIM * HDIM;      // 262144
    float4 v;
    ushort* dst;
    if (idx < N_XH) {
        int b = idx / KCAT, k = idx - b * KCAT;
        v = (k < IDIM) ? *(const float4*)&x[b * IDIM + k]
                       : *(const float4*)&h[b * HDIM + (k - IDIM)];
        dst = &xh[idx];
    } else if ((idx -= N_XH) < N_AW0) {
        v = *(const float4*)&aw0[idx]; dst = &baw0[idx];
    } else if ((idx -= N_AW0) < N_AW1) {
        v = *(const float4*)&aw1[idx]; dst = &baw1[idx];
    } else if ((idx -= N_AW1) < N_WCAT) {
        int o = idx / KCAT, k = idx - o * KCAT;
        v = (k < IDIM) ? *(const float4*)&w_ih[o * IDIM + k]
                       : *(const float4*)&w_hh[o * HDIM + (k - IDIM)];
        dst = &wcat[idx];
    } else if ((idx -= N_WCAT) < N_OW0) {
        v = *(const float4*)&ow0[idx]; dst = &bow0[idx];
    } else {
        return;
    }
    ushort4 o4 = { f2bf(v.x), f2bf(v.y), f2bf(v.z), f2bf(v.w) };
    *(ushort4*)dst = o4;
}

// ---------------- staged GEMM (small GEMMs; R8-proven) ----------------
template<int RELU_BF16, int NFRAG>
__global__ void __launch_bounds__(256) staged_gemm(
        const ushort* __restrict__ A, const ushort* __restrict__ W,
        const float* __restrict__ bias, void* __restrict__ outp,
        int Kdim, int out_ld) {
    __shared__ ushort As[2][4096];
    __shared__ ushort Ws[2][NFRAG * 1024];
    const int tid = threadIdx.x;
    const int lane = tid & 63, wave = tid >> 6;
    const int wm = wave >> 1, wn = wave & 1;
    const int r = lane & 15, g = lane >> 4;
    const int rb = blockIdx.x & 63, cb = blockIdx.x >> 6;
    const int row0 = rb * 128, col0 = cb * (NFRAG * 32);
    const int s_row = tid >> 2;
    const int s_sw = ((tid & 3) ^ ((s_row >> 1) & 3)) * 8;

    const ushort* aBase = A + (size_t)(row0 + s_row) * Kdim + s_sw;
    const ushort* wBase = W + (size_t)(col0 + s_row) * Kdim + s_sw;
    const int step64 = 64 * Kdim;
    const int rsw = (g ^ ((r >> 1) & 3)) * 8;

    f32x4 acc[4][NFRAG] = {};

    auto stage = [&](int buf, int t) {
        const int o = t * 32;
        gld_lds16(aBase + o,          &As[buf][wave * 512]);
        gld_lds16(aBase + o + step64, &As[buf][2048 + wave * 512]);
        gld_lds16(wBase + o,          &Ws[buf][wave * 512]);
        if (NFRAG == 4)
            gld_lds16(wBase + o + step64, &Ws[buf][2048 + wave * 512]);
    };
    auto compute = [&](int buf) {
        bf16x8 af[4], wf[NFRAG];
#pragma unroll
        for (int t = 0; t < 4; t++)
            af[t] = *(const bf16x8*)&As[buf][(wm * 4 + t) * 512 + r * 32 + rsw];
#pragma unroll
        for (int t = 0; t < NFRAG; t++)
            wf[t] = *(const bf16x8*)&Ws[buf][(wn * NFRAG + t) * 512 + r * 32 + rsw];
#pragma unroll
        for (int m = 0; m < 4; m++)
#pragma unroll
            for (int n = 0; n < NFRAG; n++)
                acc[m][n] = mfma16(af[m], wf[n], acc[m][n]);
    };

    stage(0, 0);
    __syncthreads();
    const int NT = Kdim >> 5;
    int cur = 0;
    for (int t = 0; t < NT - 1; t++) {
        stage(cur ^ 1, t + 1);
        compute(cur);
        __syncthreads();
        cur ^= 1;
    }
    compute(cur);

#pragma unroll
    for (int n = 0; n < NFRAG; n++) {
        int col = col0 + wn * (NFRAG * 16) + n * 16 + r;
        float bv = bias[col];
#pragma unroll
        for (int m = 0; m < 4; m++) {
            int rbase = row0 + wm * 64 + m * 16 + g * 4;
#pragma unroll
            for (int reg = 0; reg < 4; reg++) {
                float v = acc[m][n][reg] + bv;
                if (RELU_BF16) {
                    v = v > 0.f ? v : 0.f;
                    ((ushort*)outp)[(size_t)(rbase + reg) * out_ld + col] = f2bf(v);
                } else {
                    ((float*)outp)[(size_t)(rbase + reg) * out_ld + col] = v;
                }
            }
        }
    }
}

// ---------------- rowwise softmax + attn out + x_att into xh ----------------
__global__ void __launch_bounds__(256) attn_softmax(
        const float* __restrict__ logits, const float* __restrict__ x,
        float* __restrict__ attn_out, ushort* __restrict__ xh) {
    const int wave = threadIdx.x >> 6, lane = threadIdx.x & 63;
    const int row = blockIdx.x * 4 + wave;
    float v[4];
    float m = -1e30f;
#pragma unroll
    for (int i = 0; i < 4; i++) {
        v[i] = logits[row * IDIM + i * 64 + lane];
        m = fmaxf(m, v[i]);
    }
#pragma unroll
    for (int s = 32; s; s >>= 1) m = fmaxf(m, __shfl_xor(m, s, 64));
    float sum = 0.f;
#pragma unroll
    for (int i = 0; i < 4; i++) { v[i] = __expf(v[i] - m); sum += v[i]; }
#pragma unroll
    for (int s = 32; s; s >>= 1) sum += __shfl_xor(sum, s, 64);
    float inv = 1.f / sum;
#pragma unroll
    for (int i = 0; i < 4; i++) {
        int idx = i * 64 + lane;
        float a = v[i] * inv;
        attn_out[row * IDIM + idx] = a;
        xh[row * KCAT + idx] = f2bf(x[row * IDIM + idx] * a);
    }
}

// ---------------- gates GEMM: m201-style 8-phase 256x256 + LSTM epilogue ----------------
// gates = [x_att|h] @ [w_ih|w_hh]^T : M=8192, j=512, 4 gates, K=768.
// BM=BN=256 (256 cols = 4 gates x 64 j), BK=64, 8 waves (2M x 4N), wave out 128x64.
// Grid 32 rb x 8 cb = 256 blocks = 1/CU. LDS 128KB: 2 dbuf x (A 32KB + B 32KB).
// K-tiles NT=12. Per tile: 4 phases; phase = {stage 1 half-tile of tile t+1;
// counted vmcnt; barrier; ds_read next quadrant's frags (overlaps MFMA);
// MFMA prev quadrant; barrier}. Quadrants pipelined one phase:
//   stage order per tile: A0,B0,B1,A1 (halves: A rows 0-127/128-255; B cols 0-127/128-255)
//   reads:  p0: af_lo+bf0 | p1: bf1 | p2: af_hi | p3: -
//   MFMA:   p0: Q11(prev) | p1: Q00 | p2: Q01   | p3: Q10
// vmcnt(6) = 3 half-tiles in flight (proof: at phase p of tile kt, staged-through
// ht g=4(kt+1)+p; reads need ht<=4kt+1+p' -> in-flight <= 3 ht = 6 loads).
// Tail kt=NT-1: no stage; vmcnt(4),(2),(0). Every wave stages 2 loads per
// half-tile in identical order -> per-wave vmcnt + barrier = cross-wave safe.
// LDS swizzle (both-sides): chunk c of row rr stored at slot c^(rr&7) within the
// row's 128B; global source pre-swizzled within the same 128B line (coalescing
// kept); fragment reads apply same XOR -> 2 lanes/bank-quad = conflict-free.
#define MMAQ(AF, BF, MH, NH)                                                  \
    do {                                                                      \
        __builtin_amdgcn_s_setprio(1);                                        \
        _Pragma("unroll") for (int kh = 0; kh < 2; kh++)                      \
        _Pragma("unroll") for (int mf = 0; mf < 4; mf++)                      \
        _Pragma("unroll") for (int nf = 0; nf < 2; nf++)                      \
            acc[(MH)*4 + mf][(NH)*2 + nf] =                                   \
                mfma16(AF[kh][mf], BF[kh][nf], acc[(MH)*4 + mf][(NH)*2 + nf]);\
        __builtin_amdgcn_s_setprio(0);                                        \
    } while (0)

#define READ_AF(AF, buf, MH)                                                  \
    do {                                                                      \
        _Pragma("unroll") for (int kh = 0; kh < 2; kh++)                      \
        _Pragma("unroll") for (int mf = 0; mf < 4; mf++)                      \
            AF[kh][mf] = *(const bf16x8*)&As[(buf)*16384 +                    \
                (wm*128 + (MH)*64 + mf*16 + r)*64 + ((kh*4 + g) ^ (r & 7))*8];\
    } while (0)

#define READ_BF(BF, buf, NH)                                                  \
    do {                                                                      \
        _Pragma("unroll") for (int kh = 0; kh < 2; kh++)                      \
        _Pragma("unroll") for (int nf = 0; nf < 2; nf++)                      \
            BF[kh][nf] = *(const bf16x8*)&Ws[(buf)*16384 +                    \
                (wn*64 + ((NH)*2 + nf)*16 + r)*64 + ((kh*4 + g) ^ (r & 7))*8];\
    } while (0)

__global__ void __launch_bounds__(512, 2) gates_staged(
        const ushort* __restrict__ A, const ushort* __restrict__ W,
        const float* __restrict__ b_ih, const float* __restrict__ b_hh,
        const float* __restrict__ c_in,
        float* __restrict__ h_out, float* __restrict__ c_out,
        ushort* __restrict__ h_bf) {
    __shared__ ushort As[2 * 16384];   // 64KB: 2 bufs x 256 rows x 64 k
    __shared__ ushort Ws[2 * 16384];   // 64KB
    const int tid = threadIdx.x;
    const int lane = tid & 63, wave = tid >> 6;
    const int wm = wave >> 2, wn = wave & 3;    // 2M x 4N
    const int r = lane & 15, g = lane >> 4;
    const int rl = lane >> 3, ch = lane & 7;    // staging: row-in-8, chunk slot
    const int rb = blockIdx.x & 31;             // 0..31 (XCD-local A-panel reuse)
    const int cb = blockIdx.x >> 5;             // 0..7
    const int row0 = rb * 256;
    const int j0 = cb * 64;

    // W row for LDS col cc: gate=(cc>>4)&3, j = j0 + (cc&15) + ((cc>>6)<<4)
    auto wrow = [&](int cc) {
        return ((cc >> 4) & 3) * HDIM + j0 + (cc & 15) + ((cc >> 6) << 4);
    };
    // Staging sources (kt=0 baked; advance +64/tile). Wave w, instr i covers
    // 8 rows: tile_row = half*128 + w*16 + i*8 + rl; chunk src = ch ^ rl.
    const int swz = (ch ^ (rl & 7)) * 8;
    const ushort* aS[2][2];   // [mh][i]
    const ushort* bS[2][2];   // [nh][i]
#pragma unroll
    for (int hh = 0; hh < 2; hh++)
#pragma unroll
        for (int i = 0; i < 2; i++) {
            int trow = hh * 128 + wave * 16 + i * 8 + rl;
            aS[hh][i] = A + (size_t)(row0 + trow) * KCAT + swz;
            bS[hh][i] = W + (size_t)wrow(trow) * KCAT + swz;
        }

    f32x4 acc[8][4] = {};
    bf16x8 af_lo[2][4], af_hi[2][4], bf0[2][2], bf1[2][2];

    auto stageA = [&](int buf, int mh) {
        ushort* d = As + buf * 16384 + (mh * 128 + wave * 16) * 64;
        gld_lds16(aS[mh][0], d);
        gld_lds16(aS[mh][1], d + 512);
    };
    auto stageB = [&](int buf, int nh) {
        ushort* d = Ws + buf * 16384 + (nh * 128 + wave * 16) * 64;
        gld_lds16(bS[nh][0], d);
        gld_lds16(bS[nh][1], d + 512);
    };
    auto advance = [&]() {
#pragma unroll
        for (int hh = 0; hh < 2; hh++)
#pragma unroll
            for (int i = 0; i < 2; i++) { aS[hh][i] += 64; bS[hh][i] += 64; }
    };

    const int NT = KCAT / 64;   // 12
    // prologue: stage tile 0 (order A0,B0,B1,A1), then sources point at tile 1
    stageA(0, 0); stageB(0, 0); stageB(0, 1); stageA(0, 1);
    advance();

    int cur = 0;
    for (int kt = 0; kt < NT; ++kt) {
        const int nb = cur ^ 1;
        const bool st = (kt + 1 < NT);
        // ---- phase 0: stage A0(t+1); certify A0,B0(t); read af_lo,bf0; MFMA Q11(prev)
        if (st) { stageA(nb, 0); asm volatile("s_waitcnt vmcnt(6)" ::: "memory"); }
        else    {                asm volatile("s_waitcnt vmcnt(4)" ::: "memory"); }
        __builtin_amdgcn_s_barrier();
        READ_AF(af_lo, cur, 0);
        READ_BF(bf0, cur, 0);
        if (kt > 0) MMAQ(af_hi, bf1, 1, 1);
        __builtin_amdgcn_s_barrier();
        // ---- phase 1: stage B0(t+1); certify B1(t); read bf1; MFMA Q00
        if (st) { stageB(nb, 0); asm volatile("s_waitcnt vmcnt(6)" ::: "memory"); }
        else    {                asm volatile("s_waitcnt vmcnt(2)" ::: "memory"); }
        __builtin_amdgcn_s_barrier();
        READ_BF(bf1, cur, 1);
        MMAQ(af_lo, bf0, 0, 0);
        __builtin_amdgcn_s_barrier();
        // ---- phase 2: stage B1(t+1); certify A1(t); read af_hi; MFMA Q01
        if (st) { stageB(nb, 1); asm volatile("s_waitcnt vmcnt(6)" ::: "memory"); }
        else    {                asm volatile("s_waitcnt vmcnt(0)" ::: "memory"); }
        __builtin_amdgcn_s_barrier();
        READ_AF(af_hi, cur, 1);
        MMAQ(af_lo, bf1, 0, 1);
        __builtin_amdgcn_s_barrier();
        // ---- phase 3: stage A1(t+1); MFMA Q10
        if (st) stageA(nb, 1);
        __builtin_amdgcn_s_barrier();
        MMAQ(af_hi, bf0, 1, 0);
        __builtin_amdgcn_s_barrier();
        if (st) advance();
        cur = nb;
    }
    MMAQ(af_hi, bf1, 1, 1);   // drain: Q11 of last tile

    // LSTM epilogue: lane-local. j fixed per lane; gate = acc n-index.
    const int j = j0 + wn * 16 + r;
    float bb[4];
#pragma unroll
    for (int n = 0; n < 4; n++) bb[n] = b_ih[n * HDIM + j] + b_hh[n * HDIM + j];
#pragma unroll
    for (int m = 0; m < 8; m++) {
        int rbase = row0 + wm * 128 + (m >> 2) * 64 + (m & 3) * 16 + g * 4;
#pragma unroll
        for (int reg = 0; reg < 4; reg++) {
            int row = rbase + reg;
            float ig = sigmoidf_(acc[m][0][reg] + bb[0]);
            float fg = sigmoidf_(acc[m][1][reg] + bb[1]);
            float gg = tanhf_(acc[m][2][reg] + bb[2]);
            float og = sigmoidf_(acc[m][3][reg] + bb[3]);
            float cn = fg * c_in[(size_t)row * HDIM + j] + ig * gg;
            float hn = og * tanhf_(cn);
            c_out[(size_t)row * HDIM + j] = cn;
            h_out[(size_t)row * HDIM + j] = hn;
            h_bf[(size_t)row * HDIM + j] = f2bf(hn);
        }
    }
}

// ---------------- head GEMV: out = sigmoid(hrelu . ow1 + ob1) ----------------
__global__ void __launch_bounds__(256) head_gemv(
        const ushort* __restrict__ Hrelu, const float* __restrict__ ow1,
        const float* __restrict__ ob1, float* __restrict__ outp) {
    const int wave = threadIdx.x >> 6, lane = threadIdx.x & 63;
    const int row = blockIdx.x * 4 + wave;
    typedef ushort u16x8 __attribute__((ext_vector_type(8)));
    u16x8 hv = *(const u16x8*)&Hrelu[(size_t)row * HDIM + lane * 8];
    float4 w0 = *(const float4*)&ow1[lane * 8];
    float4 w1 = *(const float4*)&ow1[lane * 8 + 4];
    float s = bf2f(hv[0]) * w0.x + bf2f(hv[1]) * w0.y + bf2f(hv[2]) * w0.z +
              bf2f(hv[3]) * w0.w + bf2f(hv[4]) * w1.x + bf2f(hv[5]) * w1.y +
              bf2f(hv[6]) * w1.z + bf2f(hv[7]) * w1.w;
#pragma unroll
    for (int sh = 32; sh; sh >>= 1) s += __shfl_xor(s, sh, 64);
    if (lane == 0) outp[row] = 1.f / (1.f + __expf(-(s + ob1[0])));
}

extern "C" void kernel_launch(void* const* d_in, const int* in_sizes, int n_in,
                              void* d_out, int out_size, void* d_ws, size_t ws_size,
                              hipStream_t stream) {
    const float* x    = (const float*)d_in[0];
    const float* h    = (const float*)d_in[1];
    const float* c    = (const float*)d_in[2];
    const float* aw0  = (const float*)d_in[3];
    const float* ab0  = (const float*)d_in[4];
    const float* aw1  = (const float*)d_in[5];
    const float* ab1  = (const float*)d_in[6];
    const float* w_ih = (const float*)d_in[7];
    const float* b_ih = (const float*)d_in[8];
    const float* w_hh = (const float*)d_in[9];
    const float* b_hh = (const float*)d_in[10];
    const float* ow0  = (const float*)d_in[11];
    const float* ob0  = (const float*)d_in[12];
    const float* ow1  = (const float*)d_in[13];
    const float* ob1  = (const float*)d_in[14];

    char* ws = (char*)d_ws;
    ushort* xh     = (ushort*)(ws + 0);           // 8192*768*2  = 12582912
    ushort* a0     = (ushort*)(ws + 12582912);    // 8192*256*2  = 4194304
    float*  logits = (float*) (ws + 16777216);    // 8192*256*4  = 8388608
    ushort* hrelu  = (ushort*)(ws + 16777216);    // aliases logits (dead after softmax)
    ushort* hbf    = (ushort*)(ws + 25165824);    // 8192*512*2  = 8388608
    ushort* baw0   = (ushort*)(ws + 33554432);    // 256*768*2   = 393216
    ushort* baw1   = (ushort*)(ws + 33947648);    // 256*256*2   = 131072
    ushort* wcat   = (ushort*)(ws + 34078720);    // 2048*768*2  = 3145728
    ushort* bow0   = (ushort*)(ws + 37224448);    // 512*512*2   = 524288

    float* outv    = (float*)d_out;               // [8192]
    float* h_out   = outv + 8192;                 // [8192,512]
    float* c_out   = outv + 4202496;              // [8192,512]
    float* attn_o  = outv + 8396800;              // [8192,256]

    prep_kernel<<<8192, 256, 0, stream>>>(x, h, aw0, aw1, w_ih, w_hh, ow0,
                                          xh, baw0, baw1, wcat, bow0);
    // a0 = relu(xh @ aw0^T + ab0)         M=8192 N=256 K=768 -> 64x4 = 256 blocks
    staged_gemm<1, 2><<<256, 256, 0, stream>>>(xh, baw0, ab0, a0, KCAT, IDIM);
    // logits = a0 @ aw1^T + ab1           M=8192 N=256 K=256 -> 64x4 = 256 blocks
    staged_gemm<0, 2><<<256, 256, 0, stream>>>(a0, baw1, ab1, logits, IDIM, IDIM);
    attn_softmax<<<2048, 256, 0, stream>>>(logits, x, attn_o, xh);
    // fused LSTM gates                    M=8192 N=2048 K=768 -> 32x8 = 256 blocks
    gates_staged<<<256, 512, 0, stream>>>(xh, wcat, b_ih, b_hh, c,
                                          h_out, c_out, hbf);
    // hrelu = relu(h_new @ ow0^T + ob0)   M=8192 N=512 K=512 -> 64x4 = 256 blocks
    staged_gemm<1, 4><<<256, 256, 0, stream>>>(hbf, bow0, ob0, hrelu, HDIM, HDIM);
    head_gemv<<<2048, 256, 0, stream>>>(hrelu, ow1, ob1, outv);
}